// Round 11
// baseline (114.012 us; speedup 1.0000x reference)
//
#include <hip/hip_runtime.h>
#include <math.h>

#define N_LAYERS 200
#define KSIZE 7
#define L_IN 1388
#define FC_IN 188
#define FC_OUT 91
#define NT 256        // 4 waves: 2 rows per block, 2 waves per row
#define NSTAGES 13    // 12 stages of 16 layers (margin 96) + 1 of 8 (margin 48)
#define LBUF_N 1376   // max repack read index 1365 -> pad (floats)

typedef float v2f __attribute__((ext_vector_type(2)));

// ---- Stage tables (2-wave split per row, margin = 6 * stage_layers) ----
constexpr int s_lo(int s)  { return 16 * s; }
constexpr int s_hi(int s)  { return (s < 12) ? 16 * s + 16 : N_LAYERS; }
constexpr int lin_(int s)  { return L_IN - 6 * s_lo(s); }
constexpr int lout_(int s) { return L_IN - 6 * s_hi(s); }
constexpr int cut_(int s)  { return lout_(s) / 2; }   // all cuts even
constexpr int marg_(int s) { return 6 * (s_hi(s) - s_lo(s)); }
constexpr int s_R(int s) {
    const int a = cut_(s) + marg_(s);
    const int b = lin_(s) - cut_(s);
    const int m = (a > b) ? a : b;
    return (m + 63) / 64;
}
// Even-rounded R for split-pair storage: 12,12,12,10,10,8,8,8,6,6,6,4,4
constexpr int s_Re(int s) { return (s_R(s) + 1) & ~1; }

// lane i <- lane i+1 (wave_shl:1 = ctrl 0x130). Lane 63 gets 0 via
// bound_ctrl -> lands in the garbage-creep margin.
__device__ __forceinline__ float dpp_next(float v) {
    return __int_as_float(
        __builtin_amdgcn_mov_dpp(__float_as_int(v), 0x130, 0xf, 0xf, true));
}
__device__ __forceinline__ v2f dpp_next2(v2f v) {
    v2f o; o.x = dpp_next(v.x); o.y = dpp_next(v.y); return o;
}

__device__ __forceinline__ v2f pk_fma(v2f a, v2f b, v2f c) {
    return __builtin_elementwise_fma(a, b, c);   // -> v_pk_fma_f32
}
__device__ __forceinline__ v2f pk_max0(v2f a) {
    return __builtin_elementwise_max(a, (v2f)(0.0f));  // -> v_pk_max_f32
}

// 4-layer weight group, pre-splatted pairs {w,w} read from LDS.
// NOTE: elementwise loads only — no pointer-cast aggregate copies (rounds
// 2/7: casting defeats SROA, WG lands in scratch, VGPR=40 signature).
struct WG { v2f w2[28]; v2f b2[4]; };

__device__ __forceinline__ void load_wg(WG& wg, const v2f* wbuf2,
                                        const v2f* bbuf2, int g) {
#pragma unroll
    for (int t = 0; t < 28; ++t) wg.w2[t] = wbuf2[g * 28 + t];
#pragma unroll
    for (int j = 0; j < 4; ++j) wg.b2[j] = bbuf2[g * 4 + j];
}

// 4 layers, R positions/lane in SPLIT-PAIR layout: pair j = {x[o+j],
// x[o+j+P]} (lo/hi halves of the lane's R=2P consecutive positions).
// Every tap d then reads an ALIGNED pair:
//   src(j,d) = r2[j+d]            for j+d < P
//            = C[j+d-P]           otherwise, where
//   C[t] = {r2[t].y, dpp(r2[t].x)}   (t < P)   — 1 mov + 1 dpp
//   C[t] = dpp_next2(C[t-P])         (t >= P)  — multi-hop for small P
// This removes the misaligned-pair M-build of the adjacent-pair layout
// (~10 movs/layer at P=6). 12 halo ops/layer flat, all P.
//  - writing r2[j] ascending is safe: output j' reads only pairs >= j'.
//  - garbage creeps left 6/layer into the stage margin (unchanged).
template<int R, bool NR3>
__device__ __forceinline__ void run4(v2f (&r2)[6], const WG& wg) {
    constexpr int P = R / 2;
#pragma unroll
    for (int jj = 0; jj < 4; ++jj) {
        v2f C[6];
        {
            constexpr int NC = (P < 6) ? P : 6;
#pragma unroll
            for (int t = 0; t < NC; ++t) {
                v2f c; c.x = r2[t].y; c.y = dpp_next(r2[t].x);
                C[t] = c;
            }
#pragma unroll
            for (int t = NC; t < 6; ++t) C[t] = dpp_next2(C[t - P]);
        }
        const bool relu = !(NR3 && jj == 3);
#pragma unroll
        for (int j = 0; j < P; ++j) {
            v2f acc = wg.b2[jj];
#pragma unroll
            for (int d = 0; d < KSIZE; ++d) {
                const int m = j + d;                  // compile-time select
                const v2f src = (m < P) ? r2[m] : C[m - P];
                acc = pk_fma(wg.w2[jj * 7 + d], src, acc);
            }
            r2[j] = relu ? pk_max0(acc) : acc;
        }
    }
}

// Stage = groups [g0,g1), ping-pong weight double-buffer (LDS -> regs).
template<int R, bool FINAL>
__device__ __forceinline__ void run_stage_g(v2f (&r2)[6], WG& A,
        const v2f* wbuf2, const v2f* bbuf2, int g0, int g1) {
#pragma unroll 1
    for (int g = g0; g < g1; g += 2) {
        WG B;
        load_wg(B, wbuf2, bbuf2, (g + 1 < 50) ? g + 1 : 49);
        run4<R, false>(r2, A);
        load_wg(A, wbuf2, bbuf2, (g + 2 < 50) ? g + 2 : 49);
        run4<R, FINAL>(r2, B);
    }
}

// Cross-wave repack (position-indexed; split halves stored/loaded as b32).
// Two barriers per repack — measured (round 9): dropping one collapses duty
// 57% -> 34%. Keep both.
template<int Ro, int Rn>
__device__ __forceinline__ void repack(v2f (&r2)[6], float* lb,
                                       int lane, int rwid,
                                       int cut_o, int lout_o, int cut_n)
{
    constexpr int Po = Ro / 2, Pn = Rn / 2;
    const int base  = rwid ? cut_o : 0;
    const int bound = rwid ? lout_o : cut_o;
    const int o = base + lane * Ro;
#pragma unroll
    for (int j = 0; j < Po; ++j) {
        if (o + j < bound)      lb[o + j]      = r2[j].x;
        if (o + j + Po < bound) lb[o + j + Po] = r2[j].y;
    }
    __syncthreads();
    const int nb = (rwid ? cut_n : 0) + lane * Rn;
#pragma unroll
    for (int j = 0; j < Pn; ++j) {
        v2f v; v.x = lb[nb + j]; v.y = lb[nb + j + Pn];
        r2[j] = v;
    }
    __syncthreads();
}

template<int S>
struct Chain {
    __device__ static __forceinline__ void run(v2f (&r2)[6], WG& A,
        const v2f* wbuf2, const v2f* bbuf2, float* lbufr, int lane, int rwid)
    {
        run_stage_g<s_Re(S), false>(r2, A, wbuf2, bbuf2, 4 * S, 4 * S + 4);
        repack<s_Re(S), s_Re(S + 1)>(r2, lbufr, lane, rwid,
                                     cut_(S), lout_(S), cut_(S + 1));
        Chain<S + 1>::run(r2, A, wbuf2, bbuf2, lbufr, lane, rwid);
    }
};

template<>
struct Chain<NSTAGES - 1> {
    __device__ static __forceinline__ void run(v2f (&r2)[6], WG& A,
        const v2f* wbuf2, const v2f* bbuf2, float* lbufr, int lane, int rwid)
    {
        constexpr int R = s_Re(NSTAGES - 1);  // 4; groups 48,49 (layer 199 no ReLU)
        constexpr int P = R / 2;
        run_stage_g<R, true>(r2, A, wbuf2, bbuf2, 48, 50);
        // final gather: rwid0 owns positions [0,94), rwid1 [94,188).
        const int base  = rwid ? 94 : 0;
        const int bound = rwid ? 188 : 94;
        const int o = base + lane * R;
#pragma unroll
        for (int j = 0; j < P; ++j) {
            if (o + j < bound)     lbufr[o + j]     = r2[j].x;
            if (o + j + P < bound) lbufr[o + j + P] = r2[j].y;
        }
        __syncthreads();
    }
};

__global__ __launch_bounds__(NT, 2) void conv_chain_kernel(
    const float* __restrict__ x,
    const float* __restrict__ conv_w,
    const float* __restrict__ conv_b,
    const float* __restrict__ fc_w,
    const float* __restrict__ fc_b,
    float* __restrict__ out)
{
    // Per-row lbuf (floats): max read index 1365 -> 1376 (5.5 KB each).
    __shared__ __align__(16) float lbuf[2][LBUF_N];
    __shared__ __align__(16) v2f wbuf2[N_LAYERS * KSIZE];  // splatted {w,w}, 11.2 KB
    __shared__ __align__(16) v2f bbuf2[N_LAYERS];          // splatted {b,b}, 1.6 KB

    const int tid   = threadIdx.x;
    const int lane  = tid & 63;
    const int wid   = tid >> 6;
    const int rsel  = wid >> 1;         // which row of the pair this wave serves
    const int rwid  = wid & 1;          // wave's half within the row pipeline
    const int row   = blockIdx.x * 2 + rsel;

    float* lbufr = lbuf[rsel];

    // Pre-splat weights into LDS (one-time, shared by both rows).
    for (int i = tid; i < N_LAYERS * KSIZE; i += NT) {
        const float v = conv_w[i];
        v2f p; p.x = v; p.y = v; wbuf2[i] = p;
    }
    for (int i = tid; i < N_LAYERS; i += NT) {
        const float v = conv_b[i];
        v2f p; p.x = v; p.y = v; bbuf2[i] = p;
    }
    // Zero lbuf so garbage-margin reads are finite.
    for (int i = tid; i < 2 * LBUF_N; i += NT) lbuf[0][i] = 0.0f;

    // Stage-0 region load in split-pair layout: pair j = {x[o+j], x[o+j+P]}.
    v2f r2[6];
    const float* xr = x + (size_t)row * L_IN;
    constexpr int R0 = s_Re(0), P0 = R0 / 2;   // 12, 6
    const int c0 = rwid ? cut_(0) : 0;          // 0 or 646
    const int o0 = c0 + lane * R0;
#pragma unroll
    for (int j = 0; j < P0; ++j) {
        const int pa = o0 + j, pb = o0 + j + P0;
        v2f v;
        v.x = (pa < L_IN) ? xr[pa] : 0.0f;
        v.y = (pb < L_IN) ? xr[pb] : 0.0f;
        r2[j] = v;
    }
    __syncthreads();  // splat + zero visible before first weight read

    WG A;
    load_wg(A, wbuf2, bbuf2, 0);

    Chain<0>::run(r2, A, wbuf2, bbuf2, lbufr, lane, rwid);

    // FC(188 -> 91) + sigmoid (lbuf holds contiguous positions 0..188).
    const int pt = tid & 127;
    if (pt < FC_OUT) {
        float acc = fc_b[pt];
        const float4* wp = (const float4*)(fc_w + pt * FC_IN);
        const float4* hp = (const float4*)lbufr;
#pragma unroll 4
        for (int q = 0; q < FC_IN / 4; ++q) {
            const float4 hv = hp[q];
            const float4 wv = wp[q];
            acc = fmaf(wv.x, hv.x, acc);
            acc = fmaf(wv.y, hv.y, acc);
            acc = fmaf(wv.z, hv.z, acc);
            acc = fmaf(wv.w, hv.w, acc);
        }
        out[(size_t)row * FC_OUT + pt] = 1.0f / (1.0f + expf(-acc));
    }
}

extern "C" void kernel_launch(void* const* d_in, const int* in_sizes, int n_in,
                              void* d_out, int out_size, void* d_ws, size_t ws_size,
                              hipStream_t stream) {
    const float* x      = (const float*)d_in[0];
    const float* conv_w = (const float*)d_in[1];
    const float* conv_b = (const float*)d_in[2];
    const float* fc_w   = (const float*)d_in[3];
    const float* fc_b   = (const float*)d_in[4];
    float* outp = (float*)d_out;

    const int batch = in_sizes[0] / L_IN;  // 1024 rows, 2 rows per block
    conv_chain_kernel<<<batch / 2, NT, 0, stream>>>(x, conv_w, conv_b, fc_w, fc_b, outp);
}

// Round 12
// 113.273 us; speedup vs baseline: 1.0065x; 1.0065x over previous
//
#include <hip/hip_runtime.h>
#include <math.h>

#define N_LAYERS 200
#define KSIZE 7
#define L_IN 1388
#define FC_IN 188
#define FC_OUT 91
#define NT 256        // 4 waves; each wave owns ONE row end-to-end (no barriers)
#define NSTAGES 13    // 12 stages of 16 layers + 1 of 8

typedef float v2f __attribute__((ext_vector_type(2)));

// ---- Stage tables (wave-private row: NO cross-wave split, NO margin) ----
// Stage s enters with width w_in = 1388 - 96s; creep (6/layer) == width
// shrink, so garbage only ever occupies the already-invalid tail.
constexpr int w_in(int s) { return L_IN - 96 * s; }
// pairs per lane, sized to cover w_in: 11,11,10,9,8,8,7,6,5,5,4,3,2
constexpr int s_P(int s)  { return (w_in(s) + 127) / 128; }

// lane i <- lane i+1 (wave_shl:1 = ctrl 0x130). Lane 63 gets 0 via
// bound_ctrl -> lands in the invalid tail region.
__device__ __forceinline__ float dpp_next(float v) {
    return __int_as_float(
        __builtin_amdgcn_mov_dpp(__float_as_int(v), 0x130, 0xf, 0xf, true));
}
__device__ __forceinline__ v2f dpp_next2(v2f v) {
    v2f o; o.x = dpp_next(v.x); o.y = dpp_next(v.y); return o;
}

__device__ __forceinline__ v2f pk_fma(v2f a, v2f b, v2f c) {
    return __builtin_elementwise_fma(a, b, c);   // -> v_pk_fma_f32
}
__device__ __forceinline__ v2f pk_max0(v2f a) {
    return __builtin_elementwise_max(a, (v2f)(0.0f));  // -> v_pk_max_f32
}

// 4-layer weight group, pre-splatted pairs {w,w} read from LDS.
// NOTE: elementwise loads only — no pointer-cast aggregate copies (rounds
// 2/7: casting defeats SROA, WG lands in scratch, VGPR=40 signature).
struct WG { v2f w2[28]; v2f b2[4]; };

__device__ __forceinline__ void load_wg(WG& wg, const v2f* wbuf2,
                                        const v2f* bbuf2, int g) {
#pragma unroll
    for (int t = 0; t < 28; ++t) wg.w2[t] = wbuf2[g * 28 + t];
#pragma unroll
    for (int j = 0; j < 4; ++j) wg.b2[j] = bbuf2[g * 4 + j];
}

// 4 layers, SPLIT-PAIR layout (verbatim round-11-verified logic): pair j =
// {x[o+j], x[o+j+P]}, o = lane*2P. Every tap reads an aligned pair:
//   src(j,d) = r2[j+d] for j+d < P, else C[j+d-P];
//   C[t] = {r2[t].y, dpp(r2[t].x)}  (t < min(P,6)); multi-hop beyond.
// P in {2..6} incl. multi-hop verified by round 11 (absmax 0.0); P >= 7
// uses only the direct path (same algebra as P=6).
template<int P, bool NR3>
__device__ __forceinline__ void run4(v2f (&r2)[11], const WG& wg) {
#pragma unroll
    for (int jj = 0; jj < 4; ++jj) {
        v2f C[6];
        {
            constexpr int NC = (P < 6) ? P : 6;
#pragma unroll
            for (int t = 0; t < NC; ++t) {
                v2f c; c.x = r2[t].y; c.y = dpp_next(r2[t].x);
                C[t] = c;
            }
#pragma unroll
            for (int t = NC; t < 6; ++t) C[t] = dpp_next2(C[t - P]);
        }
        const bool relu = !(NR3 && jj == 3);
#pragma unroll
        for (int j = 0; j < P; ++j) {
            v2f acc = wg.b2[jj];
#pragma unroll
            for (int d = 0; d < KSIZE; ++d) {
                const int m = j + d;                  // compile-time select
                const v2f src = (m < P) ? r2[m] : C[m - P];
                acc = pk_fma(wg.w2[jj * 7 + d], src, acc);
            }
            r2[j] = relu ? pk_max0(acc) : acc;
        }
    }
}

// Stage = groups [g0,g1), ping-pong weight double-buffer (LDS -> regs).
template<int P, bool FINAL>
__device__ __forceinline__ void run_stage_g(v2f (&r2)[11], WG& A,
        const v2f* wbuf2, const v2f* bbuf2, int g0, int g1) {
#pragma unroll 1
    for (int g = g0; g < g1; g += 2) {
        WG B;
        load_wg(B, wbuf2, bbuf2, (g + 1 < 50) ? g + 1 : 49);
        run4<P, false>(r2, A);
        load_wg(A, wbuf2, bbuf2, (g + 2 < 50) ? g + 2 : 49);
        run4<P, FINAL>(r2, B);
    }
}

// WAVE-PRIVATE repack: relayout this wave's whole row from 2Po to 2Pn
// pairs/lane through the wave's own LDS scratch. NO barrier — only the
// LDS dependency (compiler inserts the lgkm wait; sched_barrier pins
// the write->read order). Writes cover [0,128Po), reads [0,128Pn) with
// Pn <= Po, so every read hits a fresh write.
template<int Po, int Pn>
__device__ __forceinline__ void repack(v2f (&r2)[11], float* lb, int lane) {
    const int o = lane * 2 * Po;
#pragma unroll
    for (int j = 0; j < Po; ++j) {
        lb[o + j]      = r2[j].x;
        lb[o + j + Po] = r2[j].y;
    }
    __builtin_amdgcn_sched_barrier(0);
    const int n = lane * 2 * Pn;
#pragma unroll
    for (int j = 0; j < Pn; ++j) {
        v2f v; v.x = lb[n + j]; v.y = lb[n + j + Pn];
        r2[j] = v;
    }
}

template<int S>
struct Chain {
    __device__ static __forceinline__ void run(v2f (&r2)[11], WG& A,
        const v2f* wbuf2, const v2f* bbuf2, float* lbw, int lane)
    {
        run_stage_g<s_P(S), false>(r2, A, wbuf2, bbuf2, 4 * S, 4 * S + 4);
        if constexpr (s_P(S + 1) != s_P(S)) {   // skip no-op repacks (3 of 12)
            repack<s_P(S), s_P(S + 1)>(r2, lbw, lane);
        }
        Chain<S + 1>::run(r2, A, wbuf2, bbuf2, lbw, lane);
    }
};

template<>
struct Chain<NSTAGES - 1> {
    __device__ static __forceinline__ void run(v2f (&r2)[11], WG& A,
        const v2f* wbuf2, const v2f* bbuf2, float* lbw, int lane)
    {
        constexpr int P = s_P(NSTAGES - 1);   // 2; groups 48,49 (layer 199 no ReLU)
        run_stage_g<P, true>(r2, A, wbuf2, bbuf2, 48, 50);
        // final gather: contiguous positions 0..188 valid in lbw.
        const int o = lane * 2 * P;
#pragma unroll
        for (int j = 0; j < P; ++j) {
            lbw[o + j]     = r2[j].x;
            lbw[o + j + P] = r2[j].y;
        }
        __builtin_amdgcn_sched_barrier(0);
    }
};

__global__ __launch_bounds__(NT, 1) void conv_chain_kernel(
    const float* __restrict__ x,
    const float* __restrict__ conv_w,
    const float* __restrict__ conv_b,
    const float* __restrict__ fc_w,
    const float* __restrict__ fc_b,
    float* __restrict__ out)
{
    // Per-wave row scratch: 128*P(0) = 1408 floats (5.5 KB each, 4 waves).
    __shared__ __align__(16) float lbuf[4][1408];
    __shared__ __align__(16) v2f wbuf2[N_LAYERS * KSIZE];  // splatted {w,w}, 11.2 KB
    __shared__ __align__(16) v2f bbuf2[N_LAYERS];          // splatted {b,b}, 1.6 KB

    const int tid  = threadIdx.x;
    const int lane = tid & 63;
    const int wid  = tid >> 6;
    const int row  = blockIdx.x * 4 + wid;   // one row per wave

    float* lbw = lbuf[wid];

    // Pre-splat weights into LDS (one-time, shared by the 4 waves).
    for (int i = tid; i < N_LAYERS * KSIZE; i += NT) {
        const float v = conv_w[i];
        v2f p; p.x = v; p.y = v; wbuf2[i] = p;
    }
    for (int i = tid; i < N_LAYERS; i += NT) {
        const float v = conv_b[i];
        v2f p; p.x = v; p.y = v; bbuf2[i] = p;
    }

    // Stage-0 load, split-pair layout: P0=11, pair j = {x[o+j], x[o+j+11]}.
    v2f r2[11];
    const float* xr = x + (size_t)row * L_IN;
    constexpr int P0 = s_P(0);            // 11
    const int o0 = lane * 2 * P0;
#pragma unroll
    for (int j = 0; j < P0; ++j) {
        const int pa = o0 + j, pb = o0 + j + P0;
        v2f v;
        v.x = (pa < L_IN) ? xr[pa] : 0.0f;
        v.y = (pb < L_IN) ? xr[pb] : 0.0f;
        r2[j] = v;
    }
    __syncthreads();  // weight splat visible; the ONLY block barrier

    WG A;
    load_wg(A, wbuf2, bbuf2, 0);

    Chain<0>::run(r2, A, wbuf2, bbuf2, lbw, lane);

    // FC(188 -> 91) + sigmoid, per-wave from its own lbuf.
    for (int oidx = lane; oidx < FC_OUT; oidx += 64) {
        float acc = fc_b[oidx];
        const float4* wp = (const float4*)(fc_w + oidx * FC_IN);
        const float4* hp = (const float4*)lbw;
#pragma unroll 4
        for (int q = 0; q < FC_IN / 4; ++q) {
            const float4 hv = hp[q];
            const float4 wv = wp[q];
            acc = fmaf(wv.x, hv.x, acc);
            acc = fmaf(wv.y, hv.y, acc);
            acc = fmaf(wv.z, hv.z, acc);
            acc = fmaf(wv.w, hv.w, acc);
        }
        out[(size_t)row * FC_OUT + oidx] = 1.0f / (1.0f + expf(-acc));
    }
}

extern "C" void kernel_launch(void* const* d_in, const int* in_sizes, int n_in,
                              void* d_out, int out_size, void* d_ws, size_t ws_size,
                              hipStream_t stream) {
    const float* x      = (const float*)d_in[0];
    const float* conv_w = (const float*)d_in[1];
    const float* conv_b = (const float*)d_in[2];
    const float* fc_w   = (const float*)d_in[3];
    const float* fc_b   = (const float*)d_in[4];
    float* outp = (float*)d_out;

    const int batch = in_sizes[0] / L_IN;  // 1024 rows, 4 rows per block
    conv_chain_kernel<<<batch / 4, NT, 0, stream>>>(x, conv_w, conv_b, fc_w, fc_b, outp);
}

// Round 13
// 111.804 us; speedup vs baseline: 1.0197x; 1.0131x over previous
//
#include <hip/hip_runtime.h>
#include <math.h>

#define N_LAYERS 200
#define KSIZE 7
#define L_IN 1388
#define FC_IN 188
#define FC_OUT 91
#define NT 256        // 4 waves; each wave owns ONE row end-to-end (no barriers)
#define NSTAGES 13    // 12 stages of 16 layers + 1 of 8

typedef float v2f __attribute__((ext_vector_type(2)));
typedef float v4f __attribute__((ext_vector_type(4)));

// ---- Stage tables (wave-private row: NO cross-wave split, NO margin) ----
// Stage s enters with width w_in = 1388 - 96s; creep (6/layer) == width
// shrink, so garbage only ever occupies the already-invalid tail.
constexpr int w_in(int s) { return L_IN - 96 * s; }
// pairs per lane, sized to cover w_in: 11,11,10,9,8,8,7,6,5,5,4,3,2
constexpr int s_P(int s)  { return (w_in(s) + 127) / 128; }

// lane i <- lane i+1 (wave_shl:1 = ctrl 0x130). Lane 63 gets 0 via
// bound_ctrl -> lands in the invalid tail region.
__device__ __forceinline__ float dpp_next(float v) {
    return __int_as_float(
        __builtin_amdgcn_mov_dpp(__float_as_int(v), 0x130, 0xf, 0xf, true));
}
__device__ __forceinline__ v2f dpp_next2(v2f v) {
    v2f o; o.x = dpp_next(v.x); o.y = dpp_next(v.y); return o;
}

__device__ __forceinline__ v2f pk_fma(v2f a, v2f b, v2f c) {
    return __builtin_elementwise_fma(a, b, c);   // -> v_pk_fma_f32
}
__device__ __forceinline__ v2f pk_max0(v2f a) {
    return __builtin_elementwise_max(a, (v2f)(0.0f));  // -> v_pk_max_f32
}

// 4-layer weight group as 16 float4: w4[t] = {w[2t],w[2t],w[2t+1],w[2t+1]}
// (taps splatted pairwise), b4[u] likewise for biases. Loaded as 16x
// ds_read_b128 (vs 32x b64): outstanding lgkm <= 16 per group, so the
// 4-bit lgkmcnt can express near-precise waits for the double buffer —
// the 64-outstanding b64 scheme forced over-waiting (duty loss).
// NOTE: elementwise loads only — no pointer-cast aggregate copies (rounds
// 2/7: casting defeats SROA, WG lands in scratch, VGPR=40 signature).
struct WG { v4f w4[14]; v4f b4[2]; };

__device__ __forceinline__ void load_wg(WG& wg, const v4f* wbuf4,
                                        const v4f* bbuf4, int g) {
#pragma unroll
    for (int t = 0; t < 14; ++t) wg.w4[t] = wbuf4[g * 14 + t];
#pragma unroll
    for (int u = 0; u < 2; ++u) wg.b4[u] = bbuf4[g * 2 + u];
}

// Compile-time tap/bias extraction: v4f half-select folds to subregister
// operand references (zero instructions) under full unrolling.
__device__ __forceinline__ v2f wtap(const WG& wg, int idx) {
    const v4f v = wg.w4[idx >> 1];
    v2f r;
    if (idx & 1) { r.x = v.z; r.y = v.w; } else { r.x = v.x; r.y = v.y; }
    return r;
}
__device__ __forceinline__ v2f btap(const WG& wg, int jj) {
    const v4f v = wg.b4[jj >> 1];
    v2f r;
    if (jj & 1) { r.x = v.z; r.y = v.w; } else { r.x = v.x; r.y = v.y; }
    return r;
}

// 4 layers, SPLIT-PAIR layout (round-11/12-verified): pair j = {x[o+j],
// x[o+j+P]}, o = lane*2P. Every tap reads an aligned pair:
//   src(j,d) = r2[j+d] for j+d < P, else C[j+d-P];
//   C[t] = {r2[t].y, dpp(r2[t].x)}  (t < min(P,6)); multi-hop beyond.
template<int P, bool NR3>
__device__ __forceinline__ void run4(v2f (&r2)[11], const WG& wg) {
#pragma unroll
    for (int jj = 0; jj < 4; ++jj) {
        v2f C[6];
        {
            constexpr int NC = (P < 6) ? P : 6;
#pragma unroll
            for (int t = 0; t < NC; ++t) {
                v2f c; c.x = r2[t].y; c.y = dpp_next(r2[t].x);
                C[t] = c;
            }
#pragma unroll
            for (int t = NC; t < 6; ++t) C[t] = dpp_next2(C[t - P]);
        }
        const bool relu = !(NR3 && jj == 3);
#pragma unroll
        for (int j = 0; j < P; ++j) {
            v2f acc = btap(wg, jj);
#pragma unroll
            for (int d = 0; d < KSIZE; ++d) {
                const int m = j + d;                  // compile-time select
                const v2f src = (m < P) ? r2[m] : C[m - P];
                acc = pk_fma(wtap(wg, jj * 7 + d), src, acc);
            }
            r2[j] = relu ? pk_max0(acc) : acc;
        }
    }
}

// Stage = groups [g0,g1), ping-pong weight double-buffer (LDS -> regs).
template<int P, bool FINAL>
__device__ __forceinline__ void run_stage_g(v2f (&r2)[11], WG& A,
        const v4f* wbuf4, const v4f* bbuf4, int g0, int g1) {
#pragma unroll 1
    for (int g = g0; g < g1; g += 2) {
        WG B;
        load_wg(B, wbuf4, bbuf4, (g + 1 < 50) ? g + 1 : 49);
        run4<P, false>(r2, A);
        load_wg(A, wbuf4, bbuf4, (g + 2 < 50) ? g + 2 : 49);
        run4<P, FINAL>(r2, B);
    }
}

// WAVE-PRIVATE repack: relayout this wave's whole row from 2Po to 2Pn
// pairs/lane through the wave's own LDS scratch. NO barrier — only the
// LDS dependency (compiler inserts the lgkm wait; sched_barrier pins
// the write->read order).
template<int Po, int Pn>
__device__ __forceinline__ void repack(v2f (&r2)[11], float* lb, int lane) {
    const int o = lane * 2 * Po;
#pragma unroll
    for (int j = 0; j < Po; ++j) {
        lb[o + j]      = r2[j].x;
        lb[o + j + Po] = r2[j].y;
    }
    __builtin_amdgcn_sched_barrier(0);
    const int n = lane * 2 * Pn;
#pragma unroll
    for (int j = 0; j < Pn; ++j) {
        v2f v; v.x = lb[n + j]; v.y = lb[n + j + Pn];
        r2[j] = v;
    }
}

template<int S>
struct Chain {
    __device__ static __forceinline__ void run(v2f (&r2)[11], WG& A,
        const v4f* wbuf4, const v4f* bbuf4, float* lbw, int lane)
    {
        run_stage_g<s_P(S), false>(r2, A, wbuf4, bbuf4, 4 * S, 4 * S + 4);
        if constexpr (s_P(S + 1) != s_P(S)) {   // skip no-op repacks (3 of 12)
            repack<s_P(S), s_P(S + 1)>(r2, lbw, lane);
        }
        Chain<S + 1>::run(r2, A, wbuf4, bbuf4, lbw, lane);
    }
};

template<>
struct Chain<NSTAGES - 1> {
    __device__ static __forceinline__ void run(v2f (&r2)[11], WG& A,
        const v4f* wbuf4, const v4f* bbuf4, float* lbw, int lane)
    {
        constexpr int P = s_P(NSTAGES - 1);   // 2; groups 48,49 (layer 199 no ReLU)
        run_stage_g<P, true>(r2, A, wbuf4, bbuf4, 48, 50);
        // final gather: contiguous positions 0..188 valid in lbw.
        const int o = lane * 2 * P;
#pragma unroll
        for (int j = 0; j < P; ++j) {
            lbw[o + j]     = r2[j].x;
            lbw[o + j + P] = r2[j].y;
        }
        __builtin_amdgcn_sched_barrier(0);
    }
};

__global__ __launch_bounds__(NT, 1) void conv_chain_kernel(
    const float* __restrict__ x,
    const float* __restrict__ conv_w,
    const float* __restrict__ conv_b,
    const float* __restrict__ fc_w,
    const float* __restrict__ fc_b,
    float* __restrict__ out)
{
    // Per-wave row scratch: 128*P(0) = 1408 floats (5.5 KB each, 4 waves).
    __shared__ __align__(16) float lbuf[4][1408];
    __shared__ __align__(16) v4f wbuf4[50 * 14];   // pairwise-splatted taps, 11.2 KB
    __shared__ __align__(16) v4f bbuf4[50 * 2];    // pairwise-splatted biases, 1.6 KB

    const int tid  = threadIdx.x;
    const int lane = tid & 63;
    const int wid  = tid >> 6;
    const int row  = blockIdx.x * 4 + wid;   // one row per wave

    float* lbw = lbuf[wid];

    // Pre-splat weights into LDS (one-time, shared by the 4 waves).
    // wbuf4[g*14+t] = {w[g,2t], w[g,2t], w[g,2t+1], w[g,2t+1]} with
    // w[g,k] = conv_w[g*28+k] (k = jj*7+d).
    for (int i = tid; i < 50 * 14; i += NT) {
        const int g = i / 14, t = i - g * 14;
        const float wa = conv_w[g * 28 + 2 * t];
        const float wb = conv_w[g * 28 + 2 * t + 1];
        v4f p; p.x = wa; p.y = wa; p.z = wb; p.w = wb;
        wbuf4[i] = p;
    }
    for (int i = tid; i < 50 * 2; i += NT) {
        const int g = i >> 1, u = i & 1;
        const float ba = conv_b[g * 4 + 2 * u];
        const float bb = conv_b[g * 4 + 2 * u + 1];
        v4f p; p.x = ba; p.y = ba; p.z = bb; p.w = bb;
        bbuf4[i] = p;
    }

    // Stage-0 load, split-pair layout: P0=11, pair j = {x[o+j], x[o+j+11]}.
    v2f r2[11];
    const float* xr = x + (size_t)row * L_IN;
    constexpr int P0 = s_P(0);            // 11
    const int o0 = lane * 2 * P0;
#pragma unroll
    for (int j = 0; j < P0; ++j) {
        const int pa = o0 + j, pb = o0 + j + P0;
        v2f v;
        v.x = (pa < L_IN) ? xr[pa] : 0.0f;
        v.y = (pb < L_IN) ? xr[pb] : 0.0f;
        r2[j] = v;
    }
    __syncthreads();  // weight splat visible; the ONLY block barrier

    WG A;
    load_wg(A, wbuf4, bbuf4, 0);

    Chain<0>::run(r2, A, wbuf4, bbuf4, lbw, lane);

    // FC(188 -> 91) + sigmoid, per-wave from its own lbuf.
    for (int oidx = lane; oidx < FC_OUT; oidx += 64) {
        float acc = fc_b[oidx];
        const float4* wp = (const float4*)(fc_w + oidx * FC_IN);
        const float4* hp = (const float4*)lbw;
#pragma unroll 4
        for (int q = 0; q < FC_IN / 4; ++q) {
            const float4 hv = hp[q];
            const float4 wv = wp[q];
            acc = fmaf(wv.x, hv.x, acc);
            acc = fmaf(wv.y, hv.y, acc);
            acc = fmaf(wv.z, hv.z, acc);
            acc = fmaf(wv.w, hv.w, acc);
        }
        out[(size_t)row * FC_OUT + oidx] = 1.0f / (1.0f + expf(-acc));
    }
}

extern "C" void kernel_launch(void* const* d_in, const int* in_sizes, int n_in,
                              void* d_out, int out_size, void* d_ws, size_t ws_size,
                              hipStream_t stream) {
    const float* x      = (const float*)d_in[0];
    const float* conv_w = (const float*)d_in[1];
    const float* conv_b = (const float*)d_in[2];
    const float* fc_w   = (const float*)d_in[3];
    const float* fc_b   = (const float*)d_in[4];
    float* outp = (float*)d_out;

    const int batch = in_sizes[0] / L_IN;  // 1024 rows, 4 rows per block
    conv_chain_kernel<<<batch / 4, NT, 0, stream>>>(x, conv_w, conv_b, fc_w, fc_b, outp);
}